// Round 20
// baseline (479.599 us; speedup 1.0000x reference)
//
#include <hip/hip_runtime.h>
#include <hip/hip_bf16.h>
#include <math.h>

#define D 64
#define K_CODES 8192
#define M_QUERIES 32768
#define SLICES 8
#define CODES_PER_SLICE (K_CODES / SLICES)  // 1024
#define CHUNK 32
#define NCHUNK (CODES_PER_SLICE / CHUNK)    // 32 chunks per slice
#define QPB 128                              // queries per block = 4 waves * 32
#define TAU_V 4e-3f                          // gap threshold in v units

typedef __attribute__((ext_vector_type(8))) short bf16x8;
typedef __attribute__((ext_vector_type(4))) float f32x4;
typedef __attribute__((ext_vector_type(16))) float f32x16;

__device__ __forceinline__ unsigned short f2bf(float x) {
    __hip_bfloat16 h = __float2bfloat16(x);
    return *reinterpret_cast<unsigned short*>(&h);
}
__device__ __forceinline__ float bf2f(unsigned short s) {
    __hip_bfloat16 h;
    *reinterpret_cast<unsigned short*>(&h) = s;
    return __bfloat162float(h);
}
__device__ __forceinline__ void gld_lds16(const void* g, void* l) {
    __builtin_amdgcn_global_load_lds(
        (const __attribute__((address_space(1))) void*)g,
        (__attribute__((address_space(3))) void*)l, 16, 0, 0);
}
__device__ __forceinline__ void gld_lds4(const void* g, void* l) {
    __builtin_amdgcn_global_load_lds(
        (const __attribute__((address_space(1))) void*)g,
        (__attribute__((address_space(3))) void*)l, 4, 0, 0);
}

// ---- K0: split emb into bf16 hi/lo (fragment order) + fp32 he' + fp64 ee ----
__global__ __launch_bounds__(256) void k0_split(const float* __restrict__ emb,
                                                unsigned short* __restrict__ e_hi,
                                                unsigned short* __restrict__ e_lo,
                                                float* __restrict__ halfee,
                                                double* __restrict__ eed,
                                                float* __restrict__ loss_ptr) {
    const int t = threadIdx.x;
    const int grp = blockIdx.x;                 // 64-code group
    if (grp == 0 && t == 0) *loss_ptr = 0.0f;   // k1b2 atomicAdds into it
    const int u = t & 7;
#pragma unroll
    for (int it = 0; it < 2; ++it) {
        const int r = (t >> 3) + it * 32;       // code within 64-group
        const int code = grp * 64 + r;
        const float* src = emb + ((size_t)code * 64 + u * 8);
        float4 f0 = *(const float4*)(src);
        float4 f1 = *(const float4*)(src + 4);
        float f[8] = {f0.x, f0.y, f0.z, f0.w, f1.x, f1.y, f1.z, f1.w};
        bf16x8 h, lo;
        float s = 0.f;
        double sd = 0.0;
#pragma unroll
        for (int j = 0; j < 8; ++j) {
            float e = f[j];
            s += e * e;
            sd += (double)e * (double)e;
            unsigned short hh = f2bf(e);
            h[j]  = (short)hh;
            lo[j] = (short)f2bf(e - bf2f(hh));
        }
        const int c32 = code >> 5, r32 = code & 31;
        size_t off = (size_t)c32 * 4096 + (size_t)(u * 32 + r32) * 16;
        *(bf16x8*)((char*)e_hi + off) = h;
        *(bf16x8*)((char*)e_lo + off) = lo;
        s += __shfl_xor(s, 1);
        s += __shfl_xor(s, 2);
        s += __shfl_xor(s, 4);
        sd += __shfl_xor(sd, 1);
        sd += __shfl_xor(sd, 2);
        sd += __shfl_xor(sd, 4);
        if (u == 0) {
            halfee[code] = 0.5f * s + 128.0f;
            eed[code]    = sd;                 // fp64 sum(e^2) for rescue
        }
    }
}

// ---- K1: r16/r19 known-best body + zz stashed in ws_part.w ----
__global__ __launch_bounds__(256, 1) void k1_mfma(const float* __restrict__ z,
                                                  const unsigned short* __restrict__ e_hi,
                                                  const unsigned short* __restrict__ e_lo,
                                                  const float* __restrict__ halfee,
                                                  float4* __restrict__ ws_part) {
    __shared__ __align__(16) unsigned short ldshi[2][CHUNK * 64];  // 4KB each buf
    __shared__ __align__(16) unsigned short ldslo[2][CHUNK * 64];
    __shared__ __align__(16) float ldshe[2][CHUNK];                // 128B each

    const int tid = threadIdx.x;
    const int wid = tid >> 6;    // 0..3
    const int l   = tid & 63;
    const int col = l & 31;
    const int hi  = l >> 5;
    const int slice = blockIdx.y;
    const int chunk0 = slice * NCHUNK;
    const int cbase0 = slice * CODES_PER_SLICE;

    const int qw0 = blockIdx.x * QPB + wid * 32;
    const int qrow = qw0 + col;
    bf16x8 qh[4], ql[4];
    float szz = 0.f;
#pragma unroll
    for (int kk = 0; kk < 4; ++kk) {
        const float* src = z + (size_t)qrow * D + kk * 16 + hi * 8;
        float4 f0 = *(const float4*)(src);
        float4 f1 = *(const float4*)(src + 4);
        float f[8] = {f0.x, f0.y, f0.z, f0.w, f1.x, f1.y, f1.z, f1.w};
        bf16x8 h, lo;
#pragma unroll
        for (int j = 0; j < 8; ++j) {
            szz += f[j] * f[j];
            float x = -f[j];
            unsigned short hh = f2bf(x);
            float r = x - bf2f(hh);
            h[j]  = (short)hh;
            lo[j] = (short)f2bf(r);
        }
        qh[kk] = h;
        ql[kk] = lo;
    }
    szz += __shfl_xor(szz, 32);   // both half-lanes now hold full ||z_q||^2

    float g1 = 1e30f, g2 = 1e30f;
    int   gi = 0x7fffffff;

#define STAGE(buf, c1)                                                           \
    {                                                                            \
        size_t cb = (size_t)(chunk0 + (c1)) * 4096 + wid * 1024 + l * 16;        \
        gld_lds16((const char*)e_hi + cb, (char*)&ldshi[buf][0] + wid * 1024);   \
        gld_lds16((const char*)e_lo + cb, (char*)&ldslo[buf][0] + wid * 1024);   \
        if (tid < 32)                                                            \
            gld_lds4((const char*)halfee + (size_t)(chunk0 + (c1)) * 128 + tid * 4, \
                     (char*)&ldshe[buf][0]);                                     \
    }

#define MFMA_CHUNK(bufc, acc)                                                    \
    {                                                                            \
        const char*  bh  = (const char*)ldshi[bufc];                             \
        const char*  bl  = (const char*)ldslo[bufc];                             \
        const float* bhe = ldshe[bufc];                                          \
        _Pragma("unroll") for (int g4 = 0; g4 < 4; ++g4) {                       \
            f32x4 he4 = *(const f32x4*)(bhe + g4 * 8 + 4 * hi);                  \
            _Pragma("unroll") for (int j = 0; j < 4; ++j)                        \
                acc[g4 * 4 + j] = he4[j];                                        \
        }                                                                        \
        _Pragma("unroll") for (int kk = 0; kk < 4; ++kk) {                       \
            int a0 = ((kk * 2 + hi) * 32 + col) * 16;   /* lane-contiguous */    \
            bf16x8 ah = *(const bf16x8*)(bh + a0);                               \
            bf16x8 al = *(const bf16x8*)(bl + a0);                               \
            acc = __builtin_amdgcn_mfma_f32_32x32x16_bf16(ah, qh[kk], acc, 0, 0, 0); \
            acc = __builtin_amdgcn_mfma_f32_32x32x16_bf16(ah, ql[kk], acc, 0, 0, 0); \
            acc = __builtin_amdgcn_mfma_f32_32x32x16_bf16(al, qh[kk], acc, 0, 0, 0); \
        }                                                                        \
    }

#define TOP2T(acc, cbase)                                                        \
    {                                                                            \
        float t1[8], t2[8];                                                      \
        _Pragma("unroll") for (int i = 0; i < 8; ++i) {                          \
            float va = __int_as_float((__float_as_int(acc[2 * i])     & 0xFFFFFFF0) | (2 * i));     \
            float vb = __int_as_float((__float_as_int(acc[2 * i + 1]) & 0xFFFFFFF0) | (2 * i + 1)); \
            t1[i] = fminf(va, vb);                                               \
            t2[i] = fmaxf(va, vb);                                               \
        }                                                                        \
        _Pragma("unroll") for (int s = 4; s > 0; s >>= 1) {                      \
            _Pragma("unroll") for (int i = 0; i < s; ++i) {                      \
                float m2c = fminf(t2[i], t2[i + s]);                             \
                t2[i] = __builtin_amdgcn_fmed3f(t1[i], t1[i + s], m2c);          \
                t1[i] = fminf(t1[i], t1[i + s]);                                 \
            }                                                                    \
        }                                                                        \
        float m1p = t1[0], m2p = t2[0];                                          \
        int p1 = __float_as_int(m1p) & 15;                                       \
        int code = (cbase) + (p1 & 3) + 8 * (p1 >> 2) + 4 * hi;                  \
        bool lt = m1p < g1;                                                      \
        g2 = fminf(lt ? g1 : g2, lt ? m2p : m1p);                                \
        g1 = lt ? m1p : g1;                                                      \
        gi = lt ? code : gi;                                                     \
    }

    f32x16 accE, accO;

    STAGE(0, 0);
    __syncthreads();
    STAGE(1, 1);
    MFMA_CHUNK(0, accE);
    __syncthreads();
    for (int cc = 1; cc + 1 < NCHUNK; cc += 2) {
        STAGE(0, cc + 1);
        MFMA_CHUNK(1, accO);
        TOP2T(accE, cbase0 + (cc - 1) * CHUNK);
        __syncthreads();
        if (cc + 2 < NCHUNK) STAGE(1, cc + 2);
        MFMA_CHUNK(0, accE);
        TOP2T(accO, cbase0 + cc * CHUNK);
        __syncthreads();
    }
    MFMA_CHUNK(1, accO);
    TOP2T(accE, cbase0 + (NCHUNK - 2) * CHUNK);
    TOP2T(accO, cbase0 + (NCHUNK - 1) * CHUNK);

    {
        float o1 = __shfl_xor(g1, 32);
        float o2 = __shfl_xor(g2, 32);
        int   oi = __shfl_xor(gi, 32);
        bool  take = (o1 < g1) || (o1 == g1 && oi < gi);
        float n2   = take ? fminf(o2, g1) : fminf(g2, o1);
        g1 = take ? o1 : g1;
        gi = take ? oi : gi;
        g2 = n2;
        if (l < 32) {
            int q = qw0 + col;
            ws_part[(size_t)q * SLICES + slice] =
                make_float4(g1, g2, __int_as_float(gi), szz);
        }
    }
#undef STAGE
#undef MFMA_CHUNK
#undef TOP2T
}

// ---- K1b2: merge + idx + loss + IN-BLOCK fp64 rescue (k1b+k2+k4 fused) ----
// Each block owns 256 queries: merges slices, writes idx (coalesced),
// accumulates exact d2 = zz + 2*(g1-128) into one atomicAdd (128 total),
// then rescues ITS OWN flagged near-ties (LDS list, no global coordination).
__global__ __launch_bounds__(256) void k1b2(const float4* __restrict__ ws_part,
                                            const float* __restrict__ z,
                                            const float* __restrict__ emb,
                                            const double* __restrict__ eed,
                                            int* __restrict__ ws_idx,
                                            float* __restrict__ out) {
    __shared__ int   llist[256];
    __shared__ int   lcnt;
    __shared__ float sb[256];
    __shared__ float zrow[D];
    __shared__ double rv[256];
    __shared__ int    ri[256];

    const int tid = threadIdx.x;
    if (tid == 0) lcnt = 0;
    __syncthreads();

    const int q = blockIdx.x * 256 + tid;
    float m1 = 1e30f, m2 = 1e30f, zz = 0.f;
    int   i1 = 0x7fffffff;
#pragma unroll
    for (int s = 0; s < SLICES; ++s) {
        float4 p = ws_part[(size_t)q * SLICES + s];
        float v1 = p.x, v2 = p.y;
        int   vi = __float_as_int(p.z);
        zz = p.w;
        if (v1 < m1 || (v1 == m1 && vi < i1)) { m2 = fminf(m1, v2); m1 = v1; i1 = vi; }
        else                                  { m2 = fminf(m2, v1); }
    }
    ws_idx[q] = i1;
    out[(size_t)M_QUERIES * D + q] = (float)i1;          // coalesced idx
    sb[tid] = zz + 2.0f * (m1 - 128.0f);                 // exact d2 (pre-rescue)
    if (m2 - m1 < TAU_V) {
        int r = atomicAdd(&lcnt, 1);
        llist[r] = q;
    }
    __syncthreads();
    for (int s = 128; s > 0; s >>= 1) {
        if (tid < s) sb[tid] += sb[tid + s];
        __syncthreads();
    }
    if (tid == 0)
        atomicAdd(out + (size_t)M_QUERIES * D + M_QUERIES,
                  sb[0] * (1.25f / (float)((size_t)M_QUERIES * D)));

    // rescue this block's flagged rows (fp64: s = ee64 - 2*dot64)
    const int cnt = lcnt;
    for (int r = 0; r < cnt; ++r) {
        const int rq = llist[r];
        __syncthreads();
        if (tid < D) zrow[tid] = z[(size_t)rq * D + tid];
        __syncthreads();
        double best = 1e300;
        int    bi   = 0x7fffffff;
        for (int c = tid; c < K_CODES; c += 256) {
            const float4* er = (const float4*)(emb + (size_t)c * D);
            double dot = 0.0;
#pragma unroll
            for (int k = 0; k < 16; ++k) {
                float4 e = er[k];
                dot += (double)zrow[4 * k + 0] * (double)e.x
                     + (double)zrow[4 * k + 1] * (double)e.y
                     + (double)zrow[4 * k + 2] * (double)e.z
                     + (double)zrow[4 * k + 3] * (double)e.w;
            }
            double s = fma(-2.0, dot, eed[c]);
            if (s < best) { best = s; bi = c; }          // first occurrence
        }
        rv[tid] = best;
        ri[tid] = bi;
        __syncthreads();
        for (int s = 128; s > 0; s >>= 1) {
            if (tid < s) {
                double ov = rv[tid + s];
                int    oi = ri[tid + s];
                if (ov < rv[tid] || (ov == rv[tid] && oi < ri[tid])) {
                    rv[tid] = ov;
                    ri[tid] = oi;
                }
            }
            __syncthreads();
        }
        if (tid == 0) {
            ws_idx[rq] = ri[0];
            out[(size_t)M_QUERIES * D + rq] = (float)ri[0];
        }
    }
}

// ---- K3: pure float4 gather of z_q ----
__global__ __launch_bounds__(256) void k3_gather(const float* __restrict__ emb,
                                                 const int* __restrict__ ws_idx,
                                                 float* __restrict__ out) {
    int g4 = blockIdx.x * 256 + threadIdx.x;   // float4 index, 0..524287
    int q  = g4 >> 4;
    int dd = g4 & 15;
    int id = ws_idx[q];
    float4 v = ((const float4*)(emb + (size_t)id * D))[dd];
    ((float4*)out)[g4] = v;
}

extern "C" void kernel_launch(void* const* d_in, const int* in_sizes, int n_in,
                              void* d_out, int out_size, void* d_ws, size_t ws_size,
                              hipStream_t stream) {
    const float* z   = (const float*)d_in[0];
    const float* emb = (const float*)d_in[1];
    float* out = (float*)d_out;
    char*  ws  = (char*)d_ws;

    unsigned short* e_hi    = (unsigned short*)(ws);                    // 1 MB
    unsigned short* e_lo    = (unsigned short*)(ws + 1048576);          // 1 MB
    float*          halfee  = (float*)(ws + 2097152);                   // 32 KB
    double*         eed     = (double*)(ws + 2129920);                  // 64 KB
    float4*         ws_part = (float4*)(ws + 2195456);                  // 4 MB
    int*            ws_idx  = (int*)(ws + 2195456 + 4194304);           // 128 KB

    float* loss_ptr = out + (size_t)M_QUERIES * D + M_QUERIES;

    k0_split<<<K_CODES / 64, 256, 0, stream>>>(emb, e_hi, e_lo, halfee, eed, loss_ptr);

    dim3 g1(M_QUERIES / QPB, SLICES);   // (256, 8)
    k1_mfma<<<g1, 256, 0, stream>>>(z, e_hi, e_lo, halfee, ws_part);

    k1b2<<<M_QUERIES / 256, 256, 0, stream>>>(ws_part, z, emb, eed, ws_idx, out);

    k3_gather<<<(M_QUERIES * D / 4) / 256, 256, 0, stream>>>(emb, ws_idx, out);
}

// Round 21
// 209.915 us; speedup vs baseline: 2.2847x; 2.2847x over previous
//
#include <hip/hip_runtime.h>
#include <hip/hip_bf16.h>
#include <math.h>

#define D 64
#define K_CODES 8192
#define M_QUERIES 32768
#define SLICES 8
#define CODES_PER_SLICE (K_CODES / SLICES)  // 1024
#define CHUNK 32
#define NCHUNK (CODES_PER_SLICE / CHUNK)    // 32 chunks per slice
#define QPB 128                              // queries per block = 4 waves * 32
#define TAU_V 4e-3f                          // gap threshold in v units

typedef __attribute__((ext_vector_type(8))) short bf16x8;
typedef __attribute__((ext_vector_type(4))) float f32x4;
typedef __attribute__((ext_vector_type(16))) float f32x16;

__device__ __forceinline__ unsigned short f2bf(float x) {
    __hip_bfloat16 h = __float2bfloat16(x);
    return *reinterpret_cast<unsigned short*>(&h);
}
__device__ __forceinline__ float bf2f(unsigned short s) {
    __hip_bfloat16 h;
    *reinterpret_cast<unsigned short*>(&h) = s;
    return __bfloat162float(h);
}
__device__ __forceinline__ void gld_lds16(const void* g, void* l) {
    __builtin_amdgcn_global_load_lds(
        (const __attribute__((address_space(1))) void*)g,
        (__attribute__((address_space(3))) void*)l, 16, 0, 0);
}
__device__ __forceinline__ void gld_lds4(const void* g, void* l) {
    __builtin_amdgcn_global_load_lds(
        (const __attribute__((address_space(1))) void*)g,
        (__attribute__((address_space(3))) void*)l, 4, 0, 0);
}

// ---- K0: bf16 hi/lo split (fragment order) + he' + fp64 ee + fp32 emb_T ----
// emb_T layout [g=code/256][k=dim][c=code%256] fp32: makes k2's thread-per-
// code rescue scan fully coalesced (r20 lesson: uncoalesced fp64 scan was
// ~50us/row, the session-long hidden tail cost).
__global__ __launch_bounds__(256) void k0_split(const float* __restrict__ emb,
                                                unsigned short* __restrict__ e_hi,
                                                unsigned short* __restrict__ e_lo,
                                                float* __restrict__ halfee,
                                                double* __restrict__ eed,
                                                float* __restrict__ emb_T,
                                                int* __restrict__ ws_cnt,
                                                float* __restrict__ loss_ptr) {
    const int t = threadIdx.x;
    const int grp = blockIdx.x;                 // 64-code group
    if (grp == 0 && t == 0) { *ws_cnt = 0; *loss_ptr = 0.0f; }
    const int u = t & 7;
#pragma unroll
    for (int it = 0; it < 2; ++it) {
        const int r = (t >> 3) + it * 32;       // code within 64-group
        const int code = grp * 64 + r;
        const float* src = emb + ((size_t)code * 64 + u * 8);
        float4 f0 = *(const float4*)(src);
        float4 f1 = *(const float4*)(src + 4);
        float f[8] = {f0.x, f0.y, f0.z, f0.w, f1.x, f1.y, f1.z, f1.w};
        bf16x8 h, lo;
        float s = 0.f;
        double sd = 0.0;
#pragma unroll
        for (int j = 0; j < 8; ++j) {
            float e = f[j];
            s += e * e;
            sd += (double)e * (double)e;
            unsigned short hh = f2bf(e);
            h[j]  = (short)hh;
            lo[j] = (short)f2bf(e - bf2f(hh));
        }
        const int c32 = code >> 5, r32 = code & 31;
        size_t off = (size_t)c32 * 4096 + (size_t)(u * 32 + r32) * 16;
        *(bf16x8*)((char*)e_hi + off) = h;
        *(bf16x8*)((char*)e_lo + off) = lo;
        s += __shfl_xor(s, 1);
        s += __shfl_xor(s, 2);
        s += __shfl_xor(s, 4);
        sd += __shfl_xor(sd, 1);
        sd += __shfl_xor(sd, 2);
        sd += __shfl_xor(sd, 4);
        if (u == 0) {
            halfee[code] = 0.5f * s + 128.0f;
            eed[code]    = sd;                 // fp64 sum(e^2) for rescue
        }
    }
    // emb_T build: lane cl of each wave-quarter covers code grp*64+cl,
    // dim quarter qd*16..+15. Stores are 64-lane contiguous (coalesced).
    {
        const int cl = t & 63;
        const int qd = t >> 6;                  // 0..3
        const int code = grp * 64 + cl;
        const int g = code >> 8, cmod = code & 255;
#pragma unroll
        for (int j = 0; j < 16; ++j) {
            int k = qd * 16 + j;
            emb_T[((size_t)g * 64 + k) * 256 + cmod] = emb[(size_t)code * 64 + k];
        }
    }
}

// ---- K1: r16/r19 known-best body + zz stashed in ws_part.w ----
__global__ __launch_bounds__(256, 1) void k1_mfma(const float* __restrict__ z,
                                                  const unsigned short* __restrict__ e_hi,
                                                  const unsigned short* __restrict__ e_lo,
                                                  const float* __restrict__ halfee,
                                                  float4* __restrict__ ws_part) {
    __shared__ __align__(16) unsigned short ldshi[2][CHUNK * 64];  // 4KB each buf
    __shared__ __align__(16) unsigned short ldslo[2][CHUNK * 64];
    __shared__ __align__(16) float ldshe[2][CHUNK];                // 128B each

    const int tid = threadIdx.x;
    const int wid = tid >> 6;    // 0..3
    const int l   = tid & 63;
    const int col = l & 31;
    const int hi  = l >> 5;
    const int slice = blockIdx.y;
    const int chunk0 = slice * NCHUNK;
    const int cbase0 = slice * CODES_PER_SLICE;

    const int qw0 = blockIdx.x * QPB + wid * 32;
    const int qrow = qw0 + col;
    bf16x8 qh[4], ql[4];
    float szz = 0.f;
#pragma unroll
    for (int kk = 0; kk < 4; ++kk) {
        const float* src = z + (size_t)qrow * D + kk * 16 + hi * 8;
        float4 f0 = *(const float4*)(src);
        float4 f1 = *(const float4*)(src + 4);
        float f[8] = {f0.x, f0.y, f0.z, f0.w, f1.x, f1.y, f1.z, f1.w};
        bf16x8 h, lo;
#pragma unroll
        for (int j = 0; j < 8; ++j) {
            szz += f[j] * f[j];
            float x = -f[j];
            unsigned short hh = f2bf(x);
            float r = x - bf2f(hh);
            h[j]  = (short)hh;
            lo[j] = (short)f2bf(r);
        }
        qh[kk] = h;
        ql[kk] = lo;
    }
    szz += __shfl_xor(szz, 32);   // both half-lanes hold full ||z_q||^2

    float g1 = 1e30f, g2 = 1e30f;
    int   gi = 0x7fffffff;

#define STAGE(buf, c1)                                                           \
    {                                                                            \
        size_t cb = (size_t)(chunk0 + (c1)) * 4096 + wid * 1024 + l * 16;        \
        gld_lds16((const char*)e_hi + cb, (char*)&ldshi[buf][0] + wid * 1024);   \
        gld_lds16((const char*)e_lo + cb, (char*)&ldslo[buf][0] + wid * 1024);   \
        if (tid < 32)                                                            \
            gld_lds4((const char*)halfee + (size_t)(chunk0 + (c1)) * 128 + tid * 4, \
                     (char*)&ldshe[buf][0]);                                     \
    }

#define MFMA_CHUNK(bufc, acc)                                                    \
    {                                                                            \
        const char*  bh  = (const char*)ldshi[bufc];                             \
        const char*  bl  = (const char*)ldslo[bufc];                             \
        const float* bhe = ldshe[bufc];                                          \
        _Pragma("unroll") for (int g4 = 0; g4 < 4; ++g4) {                       \
            f32x4 he4 = *(const f32x4*)(bhe + g4 * 8 + 4 * hi);                  \
            _Pragma("unroll") for (int j = 0; j < 4; ++j)                        \
                acc[g4 * 4 + j] = he4[j];                                        \
        }                                                                        \
        _Pragma("unroll") for (int kk = 0; kk < 4; ++kk) {                       \
            int a0 = ((kk * 2 + hi) * 32 + col) * 16;                            \
            bf16x8 ah = *(const bf16x8*)(bh + a0);                               \
            bf16x8 al = *(const bf16x8*)(bl + a0);                               \
            acc = __builtin_amdgcn_mfma_f32_32x32x16_bf16(ah, qh[kk], acc, 0, 0, 0); \
            acc = __builtin_amdgcn_mfma_f32_32x32x16_bf16(ah, ql[kk], acc, 0, 0, 0); \
            acc = __builtin_amdgcn_mfma_f32_32x32x16_bf16(al, qh[kk], acc, 0, 0, 0); \
        }                                                                        \
    }

#define TOP2T(acc, cbase)                                                        \
    {                                                                            \
        float t1[8], t2[8];                                                      \
        _Pragma("unroll") for (int i = 0; i < 8; ++i) {                          \
            float va = __int_as_float((__float_as_int(acc[2 * i])     & 0xFFFFFFF0) | (2 * i));     \
            float vb = __int_as_float((__float_as_int(acc[2 * i + 1]) & 0xFFFFFFF0) | (2 * i + 1)); \
            t1[i] = fminf(va, vb);                                               \
            t2[i] = fmaxf(va, vb);                                               \
        }                                                                        \
        _Pragma("unroll") for (int s = 4; s > 0; s >>= 1) {                      \
            _Pragma("unroll") for (int i = 0; i < s; ++i) {                      \
                float m2c = fminf(t2[i], t2[i + s]);                             \
                t2[i] = __builtin_amdgcn_fmed3f(t1[i], t1[i + s], m2c);          \
                t1[i] = fminf(t1[i], t1[i + s]);                                 \
            }                                                                    \
        }                                                                        \
        float m1p = t1[0], m2p = t2[0];                                          \
        int p1 = __float_as_int(m1p) & 15;                                       \
        int code = (cbase) + (p1 & 3) + 8 * (p1 >> 2) + 4 * hi;                  \
        bool lt = m1p < g1;                                                      \
        g2 = fminf(lt ? g1 : g2, lt ? m2p : m1p);                                \
        g1 = lt ? m1p : g1;                                                      \
        gi = lt ? code : gi;                                                     \
    }

    f32x16 accE, accO;

    STAGE(0, 0);
    __syncthreads();
    STAGE(1, 1);
    MFMA_CHUNK(0, accE);
    __syncthreads();
    for (int cc = 1; cc + 1 < NCHUNK; cc += 2) {
        STAGE(0, cc + 1);
        MFMA_CHUNK(1, accO);
        TOP2T(accE, cbase0 + (cc - 1) * CHUNK);
        __syncthreads();
        if (cc + 2 < NCHUNK) STAGE(1, cc + 2);
        MFMA_CHUNK(0, accE);
        TOP2T(accO, cbase0 + cc * CHUNK);
        __syncthreads();
    }
    MFMA_CHUNK(1, accO);
    TOP2T(accE, cbase0 + (NCHUNK - 2) * CHUNK);
    TOP2T(accO, cbase0 + (NCHUNK - 1) * CHUNK);

    {
        float o1 = __shfl_xor(g1, 32);
        float o2 = __shfl_xor(g2, 32);
        int   oi = __shfl_xor(gi, 32);
        bool  take = (o1 < g1) || (o1 == g1 && oi < gi);
        float n2   = take ? fminf(o2, g1) : fminf(g2, o1);
        g1 = take ? o1 : g1;
        gi = take ? oi : gi;
        g2 = n2;
        if (l < 32) {
            int q = qw0 + col;
            ws_part[(size_t)q * SLICES + slice] =
                make_float4(g1, g2, __int_as_float(gi), szz);
        }
    }
#undef STAGE
#undef MFMA_CHUNK
#undef TOP2T
}

// ---- K1b: merge + idx + near-tie list + fused loss (1 atomic per block) ----
__global__ __launch_bounds__(256) void k1b_merge(const float4* __restrict__ ws_part,
                                                 int* __restrict__ ws_idx,
                                                 int* __restrict__ ws_cnt,
                                                 int* __restrict__ ws_list,
                                                 float* __restrict__ out,
                                                 float* __restrict__ loss_ptr) {
    __shared__ float sb[256];
    const int tid = threadIdx.x;
    const int q = blockIdx.x * 256 + tid;
    float m1 = 1e30f, m2 = 1e30f, zz = 0.f;
    int   i1 = 0x7fffffff;
#pragma unroll
    for (int s = 0; s < SLICES; ++s) {
        float4 p = ws_part[(size_t)q * SLICES + s];
        float v1 = p.x, v2 = p.y;
        int   vi = __float_as_int(p.z);
        zz = p.w;
        if (v1 < m1 || (v1 == m1 && vi < i1)) { m2 = fminf(m1, v2); m1 = v1; i1 = vi; }
        else                                  { m2 = fminf(m2, v1); }
    }
    ws_idx[q] = i1;
    out[(size_t)M_QUERIES * D + q] = (float)i1;          // coalesced idx
    sb[tid] = zz + 2.0f * (m1 - 128.0f);                 // exact d2 (pre-rescue)
    if (m2 - m1 < TAU_V) {
        int r = atomicAdd(ws_cnt, 1);
        ws_list[r] = q;
    }
    __syncthreads();
    for (int s = 128; s > 0; s >>= 1) {
        if (tid < s) sb[tid] += sb[tid + s];
        __syncthreads();
    }
    if (tid == 0)
        atomicAdd(loss_ptr, sb[0] * (1.25f / (float)((size_t)M_QUERIES * D)));
}

// ---- K2: fp64 rescue, COALESCED via emb_T (thread t scans codes == t mod 256) ----
__global__ __launch_bounds__(256) void k2_rescue(const float* __restrict__ z,
                                                 const float* __restrict__ emb_T,
                                                 const double* __restrict__ eed,
                                                 const int* __restrict__ ws_cnt,
                                                 const int* __restrict__ ws_list,
                                                 int* __restrict__ ws_idx,
                                                 float* __restrict__ out) {
    __shared__ float  zrow[D];
    __shared__ double rv[256];
    __shared__ int    ri[256];
    const int tid = threadIdx.x;
    const int cnt = *ws_cnt;
    for (int r = blockIdx.x; r < cnt; r += gridDim.x) {
        const int q = ws_list[r];
        __syncthreads();
        if (tid < D) zrow[tid] = z[(size_t)q * D + tid];
        __syncthreads();
        double best = 1e300;
        int    bi   = 0x7fffffff;
        for (int g = 0; g < K_CODES / 256; ++g) {        // 32 chunks of 256 codes
            const float* base = emb_T + (size_t)g * 64 * 256 + tid;
            double d0 = 0.0, d1 = 0.0, d2 = 0.0, d3 = 0.0;
#pragma unroll
            for (int k = 0; k < 64; k += 4) {            // coalesced: lane-contig
                d0 += (double)zrow[k + 0] * (double)base[(size_t)(k + 0) * 256];
                d1 += (double)zrow[k + 1] * (double)base[(size_t)(k + 1) * 256];
                d2 += (double)zrow[k + 2] * (double)base[(size_t)(k + 2) * 256];
                d3 += (double)zrow[k + 3] * (double)base[(size_t)(k + 3) * 256];
            }
            int c = g * 256 + tid;
            double s = fma(-2.0, (d0 + d1) + (d2 + d3), eed[c]);
            if (s < best) { best = s; bi = c; }          // ascending c per thread
        }
        rv[tid] = best;
        ri[tid] = bi;
        __syncthreads();
        for (int s = 128; s > 0; s >>= 1) {
            if (tid < s) {
                double ov = rv[tid + s];
                int    oi = ri[tid + s];
                if (ov < rv[tid] || (ov == rv[tid] && oi < ri[tid])) {
                    rv[tid] = ov;
                    ri[tid] = oi;
                }
            }
            __syncthreads();
        }
        if (tid == 0) {
            ws_idx[q] = ri[0];
            out[(size_t)M_QUERIES * D + q] = (float)ri[0];
        }
        __syncthreads();
    }
}

// ---- K3: pure float4 gather of z_q ----
__global__ __launch_bounds__(256) void k3_gather(const float* __restrict__ emb,
                                                 const int* __restrict__ ws_idx,
                                                 float* __restrict__ out) {
    int g4 = blockIdx.x * 256 + threadIdx.x;   // float4 index
    int q  = g4 >> 4;
    int dd = g4 & 15;
    int id = ws_idx[q];
    float4 v = ((const float4*)(emb + (size_t)id * D))[dd];
    ((float4*)out)[g4] = v;
}

extern "C" void kernel_launch(void* const* d_in, const int* in_sizes, int n_in,
                              void* d_out, int out_size, void* d_ws, size_t ws_size,
                              hipStream_t stream) {
    const float* z   = (const float*)d_in[0];
    const float* emb = (const float*)d_in[1];
    float* out = (float*)d_out;
    char*  ws  = (char*)d_ws;

    unsigned short* e_hi    = (unsigned short*)(ws);                    // 1 MB
    unsigned short* e_lo    = (unsigned short*)(ws + 1048576);          // 1 MB
    float*          halfee  = (float*)(ws + 2097152);                   // 32 KB
    double*         eed     = (double*)(ws + 2129920);                  // 64 KB
    float*          emb_T   = (float*)(ws + 2195456);                   // 2 MB
    float4*         ws_part = (float4*)(ws + 2195456 + 2097152);        // 4 MB
    int*            ws_idx  = (int*)(ws + 2195456 + 6291456);           // 128 KB
    int*            ws_cnt  = (int*)(ws + 2195456 + 6291456 + 131072);  // 64 B
    int*            ws_list = (int*)(ws + 2195456 + 6291456 + 131136);  // 128 KB

    float* loss_ptr = out + (size_t)M_QUERIES * D + M_QUERIES;

    k0_split<<<K_CODES / 64, 256, 0, stream>>>(emb, e_hi, e_lo, halfee, eed,
                                               emb_T, ws_cnt, loss_ptr);

    dim3 g1(M_QUERIES / QPB, SLICES);   // (256, 8)
    k1_mfma<<<g1, 256, 0, stream>>>(z, e_hi, e_lo, halfee, ws_part);

    k1b_merge<<<M_QUERIES / 256, 256, 0, stream>>>(ws_part, ws_idx, ws_cnt,
                                                   ws_list, out, loss_ptr);

    k2_rescue<<<256, 256, 0, stream>>>(z, emb_T, eed, ws_cnt, ws_list, ws_idx, out);

    k3_gather<<<(M_QUERIES * D / 4) / 256, 256, 0, stream>>>(emb, ws_idx, out);
}

// Round 22
// 206.345 us; speedup vs baseline: 2.3243x; 1.0173x over previous
//
#include <hip/hip_runtime.h>
#include <hip/hip_bf16.h>
#include <math.h>

#define D 64
#define K_CODES 8192
#define M_QUERIES 32768
#define SLICES 8
#define CODES_PER_SLICE (K_CODES / SLICES)  // 1024
#define CHUNK 32
#define NCHUNK (CODES_PER_SLICE / CHUNK)    // 32 chunks per slice
#define QPB 128                              // queries per block = 4 waves * 32
#define TAU_V 4e-3f                          // gap threshold in v units

typedef __attribute__((ext_vector_type(8))) short bf16x8;
typedef __attribute__((ext_vector_type(4))) float f32x4;
typedef __attribute__((ext_vector_type(16))) float f32x16;

__device__ __forceinline__ unsigned short f2bf(float x) {
    __hip_bfloat16 h = __float2bfloat16(x);
    return *reinterpret_cast<unsigned short*>(&h);
}
__device__ __forceinline__ float bf2f(unsigned short s) {
    __hip_bfloat16 h;
    *reinterpret_cast<unsigned short*>(&h) = s;
    return __bfloat162float(h);
}
__device__ __forceinline__ void gld_lds16(const void* g, void* l) {
    __builtin_amdgcn_global_load_lds(
        (const __attribute__((address_space(1))) void*)g,
        (__attribute__((address_space(3))) void*)l, 16, 0, 0);
}
__device__ __forceinline__ void gld_lds4(const void* g, void* l) {
    __builtin_amdgcn_global_load_lds(
        (const __attribute__((address_space(1))) void*)g,
        (__attribute__((address_space(3))) void*)l, 4, 0, 0);
}

// ---- K0: bf16 hi/lo split (fragment order) + he' + fp64 ee + fp32 emb_T ----
__global__ __launch_bounds__(256) void k0_split(const float* __restrict__ emb,
                                                unsigned short* __restrict__ e_hi,
                                                unsigned short* __restrict__ e_lo,
                                                float* __restrict__ halfee,
                                                double* __restrict__ eed,
                                                float* __restrict__ emb_T,
                                                int* __restrict__ ws_cnt,
                                                float* __restrict__ loss_ptr) {
    const int t = threadIdx.x;
    const int grp = blockIdx.x;                 // 64-code group
    if (grp == 0 && t == 0) { *ws_cnt = 0; *loss_ptr = 0.0f; }
    const int u = t & 7;
#pragma unroll
    for (int it = 0; it < 2; ++it) {
        const int r = (t >> 3) + it * 32;       // code within 64-group
        const int code = grp * 64 + r;
        const float* src = emb + ((size_t)code * 64 + u * 8);
        float4 f0 = *(const float4*)(src);
        float4 f1 = *(const float4*)(src + 4);
        float f[8] = {f0.x, f0.y, f0.z, f0.w, f1.x, f1.y, f1.z, f1.w};
        bf16x8 h, lo;
        float s = 0.f;
        double sd = 0.0;
#pragma unroll
        for (int j = 0; j < 8; ++j) {
            float e = f[j];
            s += e * e;
            sd += (double)e * (double)e;
            unsigned short hh = f2bf(e);
            h[j]  = (short)hh;
            lo[j] = (short)f2bf(e - bf2f(hh));
        }
        const int c32 = code >> 5, r32 = code & 31;
        size_t off = (size_t)c32 * 4096 + (size_t)(u * 32 + r32) * 16;
        *(bf16x8*)((char*)e_hi + off) = h;
        *(bf16x8*)((char*)e_lo + off) = lo;
        s += __shfl_xor(s, 1);
        s += __shfl_xor(s, 2);
        s += __shfl_xor(s, 4);
        sd += __shfl_xor(sd, 1);
        sd += __shfl_xor(sd, 2);
        sd += __shfl_xor(sd, 4);
        if (u == 0) {
            halfee[code] = 0.5f * s + 128.0f;
            eed[code]    = sd;                 // fp64 sum(e^2) for rescue
        }
    }
    // emb_T build for k2's coalesced rescue scan
    {
        const int cl = t & 63;
        const int qd = t >> 6;                  // 0..3
        const int code = grp * 64 + cl;
        const int g = code >> 8, cmod = code & 255;
#pragma unroll
        for (int j = 0; j < 16; ++j) {
            int k = qd * 16 + j;
            emb_T[((size_t)g * 64 + k) * 256 + cmod] = emb[(size_t)code * 64 + k];
        }
    }
}

// ---- K1: r16/r19 body; __launch_bounds__(256,4) -- NOW fits without spill ----
// Unified register need is ~100 (68 VGPR + 32 AGPR acc), <= 128 budget of
// 4 waves/EU. Rounds 3-6's spill disasters were on the FAT body (~145 regs);
// this is the occupancy knob re-tested on the slim body. Watch WRITE_SIZE:
// ~5MB = clean, >>10MB = spill -> ceiling declared.
__global__ __launch_bounds__(256, 4) void k1_mfma(const float* __restrict__ z,
                                                  const unsigned short* __restrict__ e_hi,
                                                  const unsigned short* __restrict__ e_lo,
                                                  const float* __restrict__ halfee,
                                                  float4* __restrict__ ws_part) {
    __shared__ __align__(16) unsigned short ldshi[2][CHUNK * 64];  // 4KB each buf
    __shared__ __align__(16) unsigned short ldslo[2][CHUNK * 64];
    __shared__ __align__(16) float ldshe[2][CHUNK];                // 128B each

    const int tid = threadIdx.x;
    const int wid = tid >> 6;    // 0..3
    const int l   = tid & 63;
    const int col = l & 31;
    const int hi  = l >> 5;
    const int slice = blockIdx.y;
    const int chunk0 = slice * NCHUNK;
    const int cbase0 = slice * CODES_PER_SLICE;

    const int qw0 = blockIdx.x * QPB + wid * 32;
    const int qrow = qw0 + col;
    bf16x8 qh[4], ql[4];
    float szz = 0.f;
#pragma unroll
    for (int kk = 0; kk < 4; ++kk) {
        const float* src = z + (size_t)qrow * D + kk * 16 + hi * 8;
        float4 f0 = *(const float4*)(src);
        float4 f1 = *(const float4*)(src + 4);
        float f[8] = {f0.x, f0.y, f0.z, f0.w, f1.x, f1.y, f1.z, f1.w};
        bf16x8 h, lo;
#pragma unroll
        for (int j = 0; j < 8; ++j) {
            szz += f[j] * f[j];
            float x = -f[j];
            unsigned short hh = f2bf(x);
            float r = x - bf2f(hh);
            h[j]  = (short)hh;
            lo[j] = (short)f2bf(r);
        }
        qh[kk] = h;
        ql[kk] = lo;
    }
    szz += __shfl_xor(szz, 32);   // both half-lanes hold full ||z_q||^2

    float g1 = 1e30f, g2 = 1e30f;
    int   gi = 0x7fffffff;

#define STAGE(buf, c1)                                                           \
    {                                                                            \
        size_t cb = (size_t)(chunk0 + (c1)) * 4096 + wid * 1024 + l * 16;        \
        gld_lds16((const char*)e_hi + cb, (char*)&ldshi[buf][0] + wid * 1024);   \
        gld_lds16((const char*)e_lo + cb, (char*)&ldslo[buf][0] + wid * 1024);   \
        if (tid < 32)                                                            \
            gld_lds4((const char*)halfee + (size_t)(chunk0 + (c1)) * 128 + tid * 4, \
                     (char*)&ldshe[buf][0]);                                     \
    }

#define MFMA_CHUNK(bufc, acc)                                                    \
    {                                                                            \
        const char*  bh  = (const char*)ldshi[bufc];                             \
        const char*  bl  = (const char*)ldslo[bufc];                             \
        const float* bhe = ldshe[bufc];                                          \
        _Pragma("unroll") for (int g4 = 0; g4 < 4; ++g4) {                       \
            f32x4 he4 = *(const f32x4*)(bhe + g4 * 8 + 4 * hi);                  \
            _Pragma("unroll") for (int j = 0; j < 4; ++j)                        \
                acc[g4 * 4 + j] = he4[j];                                        \
        }                                                                        \
        _Pragma("unroll") for (int kk = 0; kk < 4; ++kk) {                       \
            int a0 = ((kk * 2 + hi) * 32 + col) * 16;                            \
            bf16x8 ah = *(const bf16x8*)(bh + a0);                               \
            bf16x8 al = *(const bf16x8*)(bl + a0);                               \
            acc = __builtin_amdgcn_mfma_f32_32x32x16_bf16(ah, qh[kk], acc, 0, 0, 0); \
            acc = __builtin_amdgcn_mfma_f32_32x32x16_bf16(ah, ql[kk], acc, 0, 0, 0); \
            acc = __builtin_amdgcn_mfma_f32_32x32x16_bf16(al, qh[kk], acc, 0, 0, 0); \
        }                                                                        \
    }

#define TOP2T(acc, cbase)                                                        \
    {                                                                            \
        float t1[8], t2[8];                                                      \
        _Pragma("unroll") for (int i = 0; i < 8; ++i) {                          \
            float va = __int_as_float((__float_as_int(acc[2 * i])     & 0xFFFFFFF0) | (2 * i));     \
            float vb = __int_as_float((__float_as_int(acc[2 * i + 1]) & 0xFFFFFFF0) | (2 * i + 1)); \
            t1[i] = fminf(va, vb);                                               \
            t2[i] = fmaxf(va, vb);                                               \
        }                                                                        \
        _Pragma("unroll") for (int s = 4; s > 0; s >>= 1) {                      \
            _Pragma("unroll") for (int i = 0; i < s; ++i) {                      \
                float m2c = fminf(t2[i], t2[i + s]);                             \
                t2[i] = __builtin_amdgcn_fmed3f(t1[i], t1[i + s], m2c);          \
                t1[i] = fminf(t1[i], t1[i + s]);                                 \
            }                                                                    \
        }                                                                        \
        float m1p = t1[0], m2p = t2[0];                                          \
        int p1 = __float_as_int(m1p) & 15;                                       \
        int code = (cbase) + (p1 & 3) + 8 * (p1 >> 2) + 4 * hi;                  \
        bool lt = m1p < g1;                                                      \
        g2 = fminf(lt ? g1 : g2, lt ? m2p : m1p);                                \
        g1 = lt ? m1p : g1;                                                      \
        gi = lt ? code : gi;                                                     \
    }

    f32x16 accE, accO;

    STAGE(0, 0);
    __syncthreads();
    STAGE(1, 1);
    MFMA_CHUNK(0, accE);
    __syncthreads();
    for (int cc = 1; cc + 1 < NCHUNK; cc += 2) {
        STAGE(0, cc + 1);
        MFMA_CHUNK(1, accO);
        TOP2T(accE, cbase0 + (cc - 1) * CHUNK);
        __syncthreads();
        if (cc + 2 < NCHUNK) STAGE(1, cc + 2);
        MFMA_CHUNK(0, accE);
        TOP2T(accO, cbase0 + cc * CHUNK);
        __syncthreads();
    }
    MFMA_CHUNK(1, accO);
    TOP2T(accE, cbase0 + (NCHUNK - 2) * CHUNK);
    TOP2T(accO, cbase0 + (NCHUNK - 1) * CHUNK);

    {
        float o1 = __shfl_xor(g1, 32);
        float o2 = __shfl_xor(g2, 32);
        int   oi = __shfl_xor(gi, 32);
        bool  take = (o1 < g1) || (o1 == g1 && oi < gi);
        float n2   = take ? fminf(o2, g1) : fminf(g2, o1);
        g1 = take ? o1 : g1;
        gi = take ? oi : gi;
        g2 = n2;
        if (l < 32) {
            int q = qw0 + col;
            ws_part[(size_t)q * SLICES + slice] =
                make_float4(g1, g2, __int_as_float(gi), szz);
        }
    }
#undef STAGE
#undef MFMA_CHUNK
#undef TOP2T
}

// ---- K1b: merge + idx + near-tie list + fused loss (1 atomic per block) ----
__global__ __launch_bounds__(256) void k1b_merge(const float4* __restrict__ ws_part,
                                                 int* __restrict__ ws_idx,
                                                 int* __restrict__ ws_cnt,
                                                 int* __restrict__ ws_list,
                                                 float* __restrict__ out,
                                                 float* __restrict__ loss_ptr) {
    __shared__ float sb[256];
    const int tid = threadIdx.x;
    const int q = blockIdx.x * 256 + tid;
    float m1 = 1e30f, m2 = 1e30f, zz = 0.f;
    int   i1 = 0x7fffffff;
#pragma unroll
    for (int s = 0; s < SLICES; ++s) {
        float4 p = ws_part[(size_t)q * SLICES + s];
        float v1 = p.x, v2 = p.y;
        int   vi = __float_as_int(p.z);
        zz = p.w;
        if (v1 < m1 || (v1 == m1 && vi < i1)) { m2 = fminf(m1, v2); m1 = v1; i1 = vi; }
        else                                  { m2 = fminf(m2, v1); }
    }
    ws_idx[q] = i1;
    out[(size_t)M_QUERIES * D + q] = (float)i1;          // coalesced idx
    sb[tid] = zz + 2.0f * (m1 - 128.0f);                 // exact d2 (pre-rescue)
    if (m2 - m1 < TAU_V) {
        int r = atomicAdd(ws_cnt, 1);
        ws_list[r] = q;
    }
    __syncthreads();
    for (int s = 128; s > 0; s >>= 1) {
        if (tid < s) sb[tid] += sb[tid + s];
        __syncthreads();
    }
    if (tid == 0)
        atomicAdd(loss_ptr, sb[0] * (1.25f / (float)((size_t)M_QUERIES * D)));
}

// ---- K2: fp64 rescue, coalesced via emb_T ----
__global__ __launch_bounds__(256) void k2_rescue(const float* __restrict__ z,
                                                 const float* __restrict__ emb_T,
                                                 const double* __restrict__ eed,
                                                 const int* __restrict__ ws_cnt,
                                                 const int* __restrict__ ws_list,
                                                 int* __restrict__ ws_idx,
                                                 float* __restrict__ out) {
    __shared__ float  zrow[D];
    __shared__ double rv[256];
    __shared__ int    ri[256];
    const int tid = threadIdx.x;
    const int cnt = *ws_cnt;
    for (int r = blockIdx.x; r < cnt; r += gridDim.x) {
        const int q = ws_list[r];
        __syncthreads();
        if (tid < D) zrow[tid] = z[(size_t)q * D + tid];
        __syncthreads();
        double best = 1e300;
        int    bi   = 0x7fffffff;
        for (int g = 0; g < K_CODES / 256; ++g) {
            const float* base = emb_T + (size_t)g * 64 * 256 + tid;
            double d0 = 0.0, d1 = 0.0, d2 = 0.0, d3 = 0.0;
#pragma unroll
            for (int k = 0; k < 64; k += 4) {
                d0 += (double)zrow[k + 0] * (double)base[(size_t)(k + 0) * 256];
                d1 += (double)zrow[k + 1] * (double)base[(size_t)(k + 1) * 256];
                d2 += (double)zrow[k + 2] * (double)base[(size_t)(k + 2) * 256];
                d3 += (double)zrow[k + 3] * (double)base[(size_t)(k + 3) * 256];
            }
            int c = g * 256 + tid;
            double s = fma(-2.0, (d0 + d1) + (d2 + d3), eed[c]);
            if (s < best) { best = s; bi = c; }
        }
        rv[tid] = best;
        ri[tid] = bi;
        __syncthreads();
        for (int s = 128; s > 0; s >>= 1) {
            if (tid < s) {
                double ov = rv[tid + s];
                int    oi = ri[tid + s];
                if (ov < rv[tid] || (ov == rv[tid] && oi < ri[tid])) {
                    rv[tid] = ov;
                    ri[tid] = oi;
                }
            }
            __syncthreads();
        }
        if (tid == 0) {
            ws_idx[q] = ri[0];
            out[(size_t)M_QUERIES * D + q] = (float)ri[0];
        }
        __syncthreads();
    }
}

// ---- K3: pure float4 gather of z_q ----
__global__ __launch_bounds__(256) void k3_gather(const float* __restrict__ emb,
                                                 const int* __restrict__ ws_idx,
                                                 float* __restrict__ out) {
    int g4 = blockIdx.x * 256 + threadIdx.x;   // float4 index
    int q  = g4 >> 4;
    int dd = g4 & 15;
    int id = ws_idx[q];
    float4 v = ((const float4*)(emb + (size_t)id * D))[dd];
    ((float4*)out)[g4] = v;
}

extern "C" void kernel_launch(void* const* d_in, const int* in_sizes, int n_in,
                              void* d_out, int out_size, void* d_ws, size_t ws_size,
                              hipStream_t stream) {
    const float* z   = (const float*)d_in[0];
    const float* emb = (const float*)d_in[1];
    float* out = (float*)d_out;
    char*  ws  = (char*)d_ws;

    unsigned short* e_hi    = (unsigned short*)(ws);                    // 1 MB
    unsigned short* e_lo    = (unsigned short*)(ws + 1048576);          // 1 MB
    float*          halfee  = (float*)(ws + 2097152);                   // 32 KB
    double*         eed     = (double*)(ws + 2129920);                  // 64 KB
    float*          emb_T   = (float*)(ws + 2195456);                   // 2 MB
    float4*         ws_part = (float4*)(ws + 2195456 + 2097152);        // 4 MB
    int*            ws_idx  = (int*)(ws + 2195456 + 6291456);           // 128 KB
    int*            ws_cnt  = (int*)(ws + 2195456 + 6291456 + 131072);  // 64 B
    int*            ws_list = (int*)(ws + 2195456 + 6291456 + 131136);  // 128 KB

    float* loss_ptr = out + (size_t)M_QUERIES * D + M_QUERIES;

    k0_split<<<K_CODES / 64, 256, 0, stream>>>(emb, e_hi, e_lo, halfee, eed,
                                               emb_T, ws_cnt, loss_ptr);

    dim3 g1(M_QUERIES / QPB, SLICES);   // (256, 8)
    k1_mfma<<<g1, 256, 0, stream>>>(z, e_hi, e_lo, halfee, ws_part);

    k1b_merge<<<M_QUERIES / 256, 256, 0, stream>>>(ws_part, ws_idx, ws_cnt,
                                                   ws_list, out, loss_ptr);

    k2_rescue<<<256, 256, 0, stream>>>(z, emb_T, eed, ws_cnt, ws_list, ws_idx, out);

    k3_gather<<<(M_QUERIES * D / 4) / 256, 256, 0, stream>>>(emb, ws_idx, out);
}

// Round 23
// 181.174 us; speedup vs baseline: 2.6472x; 1.1389x over previous
//
#include <hip/hip_runtime.h>
#include <hip/hip_bf16.h>
#include <math.h>

#define D 64
#define K_CODES 8192
#define M_QUERIES 32768
#define SLICES 8
#define CODES_PER_SLICE (K_CODES / SLICES)  // 1024
#define CHUNK 32
#define NCHUNK (CODES_PER_SLICE / CHUNK)    // 32 chunks per slice
#define QPB 128                              // queries per block = 4 waves * 32
#define TAU_V 4e-3f                          // gap threshold in v units

typedef __attribute__((ext_vector_type(8))) short bf16x8;
typedef __attribute__((ext_vector_type(4))) float f32x4;
typedef __attribute__((ext_vector_type(16))) float f32x16;

__device__ __forceinline__ unsigned short f2bf(float x) {
    __hip_bfloat16 h = __float2bfloat16(x);
    return *reinterpret_cast<unsigned short*>(&h);
}
__device__ __forceinline__ float bf2f(unsigned short s) {
    __hip_bfloat16 h;
    *reinterpret_cast<unsigned short*>(&h) = s;
    return __bfloat162float(h);
}
__device__ __forceinline__ void gld_lds16(const void* g, void* l) {
    __builtin_amdgcn_global_load_lds(
        (const __attribute__((address_space(1))) void*)g,
        (__attribute__((address_space(3))) void*)l, 16, 0, 0);
}
__device__ __forceinline__ void gld_lds4(const void* g, void* l) {
    __builtin_amdgcn_global_load_lds(
        (const __attribute__((address_space(1))) void*)g,
        (__attribute__((address_space(3))) void*)l, 4, 0, 0);
}

// ---- K0: bf16 hi/lo split (fragment order) + fp32 he' + fp64 ee ----
__global__ __launch_bounds__(256) void k0_split(const float* __restrict__ emb,
                                                unsigned short* __restrict__ e_hi,
                                                unsigned short* __restrict__ e_lo,
                                                float* __restrict__ halfee,
                                                double* __restrict__ eed,
                                                int* __restrict__ ws_cnt,
                                                float* __restrict__ loss_ptr) {
    const int t = threadIdx.x;
    const int grp = blockIdx.x;                 // 64-code group
    if (grp == 0 && t == 0) { *ws_cnt = 0; *loss_ptr = 0.0f; }
    const int u = t & 7;
#pragma unroll
    for (int it = 0; it < 2; ++it) {
        const int r = (t >> 3) + it * 32;       // code within 64-group
        const int code = grp * 64 + r;
        const float* src = emb + ((size_t)code * 64 + u * 8);
        float4 f0 = *(const float4*)(src);
        float4 f1 = *(const float4*)(src + 4);
        float f[8] = {f0.x, f0.y, f0.z, f0.w, f1.x, f1.y, f1.z, f1.w};
        bf16x8 h, lo;
        float s = 0.f;
        double sd = 0.0;
#pragma unroll
        for (int j = 0; j < 8; ++j) {
            float e = f[j];
            s += e * e;
            sd += (double)e * (double)e;
            unsigned short hh = f2bf(e);
            h[j]  = (short)hh;
            lo[j] = (short)f2bf(e - bf2f(hh));
        }
        const int c32 = code >> 5, r32 = code & 31;
        size_t off = (size_t)c32 * 4096 + (size_t)(u * 32 + r32) * 16;
        *(bf16x8*)((char*)e_hi + off) = h;
        *(bf16x8*)((char*)e_lo + off) = lo;
        s += __shfl_xor(s, 1);
        s += __shfl_xor(s, 2);
        s += __shfl_xor(s, 4);
        sd += __shfl_xor(sd, 1);
        sd += __shfl_xor(sd, 2);
        sd += __shfl_xor(sd, 4);
        if (u == 0) {
            halfee[code] = 0.5f * s + 128.0f;
            eed[code]    = sd;                 // fp64 sum(e^2) for rescue
        }
    }
}

// ---- K1: r22 verified-best: LDS dbuf, deferred tree-TOP2, (256,4) no-spill ----
// VGPR 60 + 32 AGPR, occupancy 34%, MfmaUtil 45 + VALUBusy 50 ~= 95% issue.
__global__ __launch_bounds__(256, 4) void k1_mfma(const float* __restrict__ z,
                                                  const unsigned short* __restrict__ e_hi,
                                                  const unsigned short* __restrict__ e_lo,
                                                  const float* __restrict__ halfee,
                                                  float4* __restrict__ ws_part) {
    __shared__ __align__(16) unsigned short ldshi[2][CHUNK * 64];  // 4KB each buf
    __shared__ __align__(16) unsigned short ldslo[2][CHUNK * 64];
    __shared__ __align__(16) float ldshe[2][CHUNK];                // 128B each

    const int tid = threadIdx.x;
    const int wid = tid >> 6;    // 0..3
    const int l   = tid & 63;
    const int col = l & 31;
    const int hi  = l >> 5;
    const int slice = blockIdx.y;
    const int chunk0 = slice * NCHUNK;
    const int cbase0 = slice * CODES_PER_SLICE;

    const int qw0 = blockIdx.x * QPB + wid * 32;
    const int qrow = qw0 + col;
    bf16x8 qh[4], ql[4];
    float szz = 0.f;
#pragma unroll
    for (int kk = 0; kk < 4; ++kk) {
        const float* src = z + (size_t)qrow * D + kk * 16 + hi * 8;
        float4 f0 = *(const float4*)(src);
        float4 f1 = *(const float4*)(src + 4);
        float f[8] = {f0.x, f0.y, f0.z, f0.w, f1.x, f1.y, f1.z, f1.w};
        bf16x8 h, lo;
#pragma unroll
        for (int j = 0; j < 8; ++j) {
            szz += f[j] * f[j];
            float x = -f[j];
            unsigned short hh = f2bf(x);
            float r = x - bf2f(hh);
            h[j]  = (short)hh;
            lo[j] = (short)f2bf(r);
        }
        qh[kk] = h;
        ql[kk] = lo;
    }
    szz += __shfl_xor(szz, 32);   // both half-lanes hold full ||z_q||^2

    float g1 = 1e30f, g2 = 1e30f;
    int   gi = 0x7fffffff;

#define STAGE(buf, c1)                                                           \
    {                                                                            \
        size_t cb = (size_t)(chunk0 + (c1)) * 4096 + wid * 1024 + l * 16;        \
        gld_lds16((const char*)e_hi + cb, (char*)&ldshi[buf][0] + wid * 1024);   \
        gld_lds16((const char*)e_lo + cb, (char*)&ldslo[buf][0] + wid * 1024);   \
        if (tid < 32)                                                            \
            gld_lds4((const char*)halfee + (size_t)(chunk0 + (c1)) * 128 + tid * 4, \
                     (char*)&ldshe[buf][0]);                                     \
    }

#define MFMA_CHUNK(bufc, acc)                                                    \
    {                                                                            \
        const char*  bh  = (const char*)ldshi[bufc];                             \
        const char*  bl  = (const char*)ldslo[bufc];                             \
        const float* bhe = ldshe[bufc];                                          \
        _Pragma("unroll") for (int g4 = 0; g4 < 4; ++g4) {                       \
            f32x4 he4 = *(const f32x4*)(bhe + g4 * 8 + 4 * hi);                  \
            _Pragma("unroll") for (int j = 0; j < 4; ++j)                        \
                acc[g4 * 4 + j] = he4[j];                                        \
        }                                                                        \
        _Pragma("unroll") for (int kk = 0; kk < 4; ++kk) {                       \
            int a0 = ((kk * 2 + hi) * 32 + col) * 16;                            \
            bf16x8 ah = *(const bf16x8*)(bh + a0);                               \
            bf16x8 al = *(const bf16x8*)(bl + a0);                               \
            acc = __builtin_amdgcn_mfma_f32_32x32x16_bf16(ah, qh[kk], acc, 0, 0, 0); \
            acc = __builtin_amdgcn_mfma_f32_32x32x16_bf16(ah, ql[kk], acc, 0, 0, 0); \
            acc = __builtin_amdgcn_mfma_f32_32x32x16_bf16(al, qh[kk], acc, 0, 0, 0); \
        }                                                                        \
    }

#define TOP2T(acc, cbase)                                                        \
    {                                                                            \
        float t1[8], t2[8];                                                      \
        _Pragma("unroll") for (int i = 0; i < 8; ++i) {                          \
            float va = __int_as_float((__float_as_int(acc[2 * i])     & 0xFFFFFFF0) | (2 * i));     \
            float vb = __int_as_float((__float_as_int(acc[2 * i + 1]) & 0xFFFFFFF0) | (2 * i + 1)); \
            t1[i] = fminf(va, vb);                                               \
            t2[i] = fmaxf(va, vb);                                               \
        }                                                                        \
        _Pragma("unroll") for (int s = 4; s > 0; s >>= 1) {                      \
            _Pragma("unroll") for (int i = 0; i < s; ++i) {                      \
                float m2c = fminf(t2[i], t2[i + s]);                             \
                t2[i] = __builtin_amdgcn_fmed3f(t1[i], t1[i + s], m2c);          \
                t1[i] = fminf(t1[i], t1[i + s]);                                 \
            }                                                                    \
        }                                                                        \
        float m1p = t1[0], m2p = t2[0];                                          \
        int p1 = __float_as_int(m1p) & 15;                                       \
        int code = (cbase) + (p1 & 3) + 8 * (p1 >> 2) + 4 * hi;                  \
        bool lt = m1p < g1;                                                      \
        g2 = fminf(lt ? g1 : g2, lt ? m2p : m1p);                                \
        g1 = lt ? m1p : g1;                                                      \
        gi = lt ? code : gi;                                                     \
    }

    f32x16 accE, accO;

    STAGE(0, 0);
    __syncthreads();
    STAGE(1, 1);
    MFMA_CHUNK(0, accE);
    __syncthreads();
    for (int cc = 1; cc + 1 < NCHUNK; cc += 2) {
        STAGE(0, cc + 1);
        MFMA_CHUNK(1, accO);
        TOP2T(accE, cbase0 + (cc - 1) * CHUNK);
        __syncthreads();
        if (cc + 2 < NCHUNK) STAGE(1, cc + 2);
        MFMA_CHUNK(0, accE);
        TOP2T(accO, cbase0 + cc * CHUNK);
        __syncthreads();
    }
    MFMA_CHUNK(1, accO);
    TOP2T(accE, cbase0 + (NCHUNK - 2) * CHUNK);
    TOP2T(accO, cbase0 + (NCHUNK - 1) * CHUNK);

    {
        float o1 = __shfl_xor(g1, 32);
        float o2 = __shfl_xor(g2, 32);
        int   oi = __shfl_xor(gi, 32);
        bool  take = (o1 < g1) || (o1 == g1 && oi < gi);
        float n2   = take ? fminf(o2, g1) : fminf(g2, o1);
        g1 = take ? o1 : g1;
        gi = take ? oi : gi;
        g2 = n2;
        if (l < 32) {
            int q = qw0 + col;
            ws_part[(size_t)q * SLICES + slice] =
                make_float4(g1, g2, __int_as_float(gi), szz);
        }
    }
#undef STAGE
#undef MFMA_CHUNK
#undef TOP2T
}

// ---- K1b: merge + idx + loss + near-tie list + GATHER (k3 folded in) ----
__global__ __launch_bounds__(256) void k1b_merge(const float4* __restrict__ ws_part,
                                                 const float* __restrict__ emb,
                                                 int* __restrict__ ws_idx,
                                                 int* __restrict__ ws_cnt,
                                                 int* __restrict__ ws_list,
                                                 float* __restrict__ out,
                                                 float* __restrict__ loss_ptr) {
    __shared__ float sb[256];
    __shared__ int   sidx[256];
    const int tid = threadIdx.x;
    const int q = blockIdx.x * 256 + tid;
    float m1 = 1e30f, m2 = 1e30f, zz = 0.f;
    int   i1 = 0x7fffffff;
#pragma unroll
    for (int s = 0; s < SLICES; ++s) {
        float4 p = ws_part[(size_t)q * SLICES + s];
        float v1 = p.x, v2 = p.y;
        int   vi = __float_as_int(p.z);
        zz = p.w;
        if (v1 < m1 || (v1 == m1 && vi < i1)) { m2 = fminf(m1, v2); m1 = v1; i1 = vi; }
        else                                  { m2 = fminf(m2, v1); }
    }
    ws_idx[q] = i1;
    sidx[tid] = i1;
    out[(size_t)M_QUERIES * D + q] = (float)i1;          // coalesced idx
    sb[tid] = zz + 2.0f * (m1 - 128.0f);                 // exact d2 (pre-rescue)
    if (m2 - m1 < TAU_V) {
        int r = atomicAdd(ws_cnt, 1);
        ws_list[r] = q;
    }
    __syncthreads();
    for (int s = 128; s > 0; s >>= 1) {
        if (tid < s) sb[tid] += sb[tid + s];
        __syncthreads();
    }
    if (tid == 0)
        atomicAdd(loss_ptr, sb[0] * (1.25f / (float)((size_t)M_QUERIES * D)));

    // gather this block's 256 z_q rows (float4; 16 threads cover one row seg)
    const float4* emb4 = (const float4*)emb;
    float4*       out4 = (float4*)out;
    const size_t  base4 = (size_t)blockIdx.x * 256 * 16;
#pragma unroll
    for (int i = 0; i < 16; ++i) {
        int g4l = tid + i * 256;              // 0..4095
        int ql  = g4l >> 4;
        int dd  = g4l & 15;
        int id  = sidx[ql];
        out4[base4 + g4l] = emb4[(size_t)id * 16 + dd];
    }
}

// ---- K2: fp64 rescue (emb + eed, 256-block parallel) + output patch ----
__global__ __launch_bounds__(256) void k2_rescue(const float* __restrict__ z,
                                                 const float* __restrict__ emb,
                                                 const double* __restrict__ eed,
                                                 const int* __restrict__ ws_cnt,
                                                 const int* __restrict__ ws_list,
                                                 int* __restrict__ ws_idx,
                                                 float* __restrict__ out) {
    __shared__ float  zrow[D];
    __shared__ double rv[256];
    __shared__ int    ri[256];
    const int tid = threadIdx.x;
    const int cnt = *ws_cnt;
    for (int r = blockIdx.x; r < cnt; r += gridDim.x) {
        const int q = ws_list[r];
        __syncthreads();
        if (tid < D) zrow[tid] = z[(size_t)q * D + tid];
        __syncthreads();
        double best = 1e300;
        int    bi   = 0x7fffffff;
        for (int c = tid; c < K_CODES; c += 256) {
            const float4* er = (const float4*)(emb + (size_t)c * D);
            double dot = 0.0;
#pragma unroll
            for (int k = 0; k < 16; ++k) {
                float4 e = er[k];
                dot += (double)zrow[4 * k + 0] * (double)e.x
                     + (double)zrow[4 * k + 1] * (double)e.y
                     + (double)zrow[4 * k + 2] * (double)e.z
                     + (double)zrow[4 * k + 3] * (double)e.w;
            }
            double s = fma(-2.0, dot, eed[c]);
            if (s < best) { best = s; bi = c; }          // first occurrence
        }
        rv[tid] = best;
        ri[tid] = bi;
        __syncthreads();
        for (int s = 128; s > 0; s >>= 1) {
            if (tid < s) {
                double ov = rv[tid + s];
                int    oi = ri[tid + s];
                if (ov < rv[tid] || (ov == rv[tid] && oi < ri[tid])) {
                    rv[tid] = ov;
                    ri[tid] = oi;
                }
            }
            __syncthreads();
        }
        const int fid = ri[0];
        if (tid == 0) {
            ws_idx[q] = fid;
            out[(size_t)M_QUERIES * D + q] = (float)fid;
        }
        if (tid < D)                                     // patch gathered row
            out[(size_t)q * D + tid] = emb[(size_t)fid * D + tid];
        __syncthreads();
    }
}

extern "C" void kernel_launch(void* const* d_in, const int* in_sizes, int n_in,
                              void* d_out, int out_size, void* d_ws, size_t ws_size,
                              hipStream_t stream) {
    const float* z   = (const float*)d_in[0];
    const float* emb = (const float*)d_in[1];
    float* out = (float*)d_out;
    char*  ws  = (char*)d_ws;

    unsigned short* e_hi    = (unsigned short*)(ws);                    // 1 MB
    unsigned short* e_lo    = (unsigned short*)(ws + 1048576);          // 1 MB
    float*          halfee  = (float*)(ws + 2097152);                   // 32 KB
    double*         eed     = (double*)(ws + 2129920);                  // 64 KB
    float4*         ws_part = (float4*)(ws + 2195456);                  // 4 MB
    int*            ws_idx  = (int*)(ws + 2195456 + 4194304);           // 128 KB
    int*            ws_cnt  = (int*)(ws + 2195456 + 4194304 + 131072);  // 64 B
    int*            ws_list = (int*)(ws + 2195456 + 4194304 + 131136);  // 128 KB

    float* loss_ptr = out + (size_t)M_QUERIES * D + M_QUERIES;

    k0_split<<<K_CODES / 64, 256, 0, stream>>>(emb, e_hi, e_lo, halfee, eed,
                                               ws_cnt, loss_ptr);

    dim3 g1(M_QUERIES / QPB, SLICES);   // (256, 8)
    k1_mfma<<<g1, 256, 0, stream>>>(z, e_hi, e_lo, halfee, ws_part);

    k1b_merge<<<M_QUERIES / 256, 256, 0, stream>>>(ws_part, emb, ws_idx, ws_cnt,
                                                   ws_list, out, loss_ptr);

    k2_rescue<<<256, 256, 0, stream>>>(z, emb, eed, ws_cnt, ws_list, ws_idx, out);
}